// Round 1
// baseline (4036.903 us; speedup 1.0000x reference)
//
#include <hip/hip_runtime.h>

#define DD 384
#define NB 64
#define NATOM 8192
#define KW 11

// ---------------------------------------------------------------------------
// Generate DFT-derived matrices:
//   theta(u,m) = 2*pi*(u-192)*(m-192)/384
//   U[u,m] = cos(theta) + sin(theta)   (cas)
//   S[u,m] = sin(theta)
// Both symmetric. y_out = U*Y*U - 2*S*Y*S  equals Re(f)-Im(f) of the
// double-fftshifted 2D FFT (shifts folded into the (u-192)(m-192) phase).
// ---------------------------------------------------------------------------
__global__ void gen_w(float* __restrict__ U, float* __restrict__ S) {
    int idx = blockIdx.x * 256 + threadIdx.x;
    if (idx >= DD * DD) return;
    int u = idx / DD, m = idx % DD;
    int t = (u - 192) * (m - 192);
    int r = t % DD;
    if (r < 0) r += DD;
    float th = (float)r * (6.28318530717958647692f / (float)DD);
    float s = sinf(th), c = cosf(th);
    U[idx] = c + s;
    S[idx] = s;
}

// ---------------------------------------------------------------------------
// Pose transform + gaussian splat. One thread per atom; 121 atomicAdds.
// Matches reference: c = x + 192; center = rint(c) (round-half-even);
// gx[k] = exp(-((ix-192) - X)^2 / (2*sigma^2)) masked to [0,384).
// ---------------------------------------------------------------------------
__global__ void pose_splat(const float* __restrict__ crd,
                           const float* __restrict__ rot,
                           const float* __restrict__ rot_init,
                           const float* __restrict__ trans,
                           float* __restrict__ img) {
    int b = blockIdx.y;
    int n = blockIdx.x * 256 + threadIdx.x;
    const float* p = crd + ((long)b * NATOM + n) * 3;
    float x0 = p[0], y0 = p[1], z0 = p[2];
    // crd @ rot_init + trans : out[j'] = sum_j crd[j]*rot_init[j][j']
    float q0 = x0 * rot_init[0] + y0 * rot_init[3] + z0 * rot_init[6] + trans[0];
    float q1 = x0 * rot_init[1] + y0 * rot_init[4] + z0 * rot_init[7] + trans[1];
    float q2 = x0 * rot_init[2] + y0 * rot_init[5] + z0 * rot_init[8] + trans[2];
    // einsum('bnj,bkj->bnk'): out[k] = sum_j q[j]*rot[b][k][j]; need k=0,1
    const float* R = rot + b * 9;
    float X = q0 * R[0] + q1 * R[1] + q2 * R[2];
    float Y = q0 * R[3] + q1 * R[4] + q2 * R[5];

    int icx = (int)rintf(X + 192.0f);
    int icy = (int)rintf(Y + 192.0f);

    const float inv2s2 = 1.0f / 4.5f;  // 1/(2*1.5^2)
    float gx[KW], gy[KW];
#pragma unroll
    for (int k = 0; k < KW; k++) {
        int ix = icx + k - 5;
        float dx = (float)(ix - 192) - X;
        gx[k] = (ix >= 0 && ix < DD) ? __expf(-dx * dx * inv2s2) : 0.0f;
        int iy = icy + k - 5;
        float dy = (float)(iy - 192) - Y;
        gy[k] = (iy >= 0 && iy < DD) ? __expf(-dy * dy * inv2s2) : 0.0f;
    }

    float* im = img + (long)b * DD * DD;
#pragma unroll
    for (int ky = 0; ky < KW; ky++) {
        if (gy[ky] == 0.0f) continue;
        int iy = icy + ky - 5;
        float* row = im + iy * DD;
#pragma unroll
        for (int kx = 0; kx < KW; kx++) {
            if (gx[kx] == 0.0f) continue;
            int ix = icx + kx - 5;
            atomicAdd(row + ix, gy[ky] * gx[kx]);
        }
    }
}

// ---------------------------------------------------------------------------
// Batched fp32 matmul: C[bz] = alpha * A[bz] x B[bz] + beta * C[bz]
// strides are per-batch element strides (0 = shared matrix).
// 64x64 tile per block, 256 threads, 4x4 micro-tile, K-chunk 16.
// ---------------------------------------------------------------------------
__global__ __launch_bounds__(256) void mm64(const float* __restrict__ A, long sA,
                                            const float* __restrict__ Bm, long sB,
                                            float* __restrict__ C, long sC,
                                            float alpha, float beta) {
    int bz = blockIdx.z;
    const float* Ab = A + (long)bz * sA;
    const float* Bb = Bm + (long)bz * sB;
    float* Cb = C + (long)bz * sC;

    __shared__ float As[16][64];
    __shared__ float Bs[16][64];

    int t = threadIdx.x;
    int m0 = blockIdx.y * 64, n0 = blockIdx.x * 64;
    int tx = t & 15, ty = t >> 4;

    float acc[4][4];
#pragma unroll
    for (int i = 0; i < 4; i++)
#pragma unroll
        for (int j = 0; j < 4; j++) acc[i][j] = 0.0f;

    for (int k0 = 0; k0 < DD; k0 += 16) {
#pragma unroll
        for (int i = 0; i < 4; i++) {
            int idx = t + i * 256;
            int m = idx >> 4, k = idx & 15;
            As[k][m] = Ab[(long)(m0 + m) * DD + k0 + k];
            int kk = idx >> 6, n = idx & 63;
            Bs[kk][n] = Bb[(long)(k0 + kk) * DD + n0 + n];
        }
        __syncthreads();
#pragma unroll
        for (int k = 0; k < 16; k++) {
            float4 a = *(const float4*)&As[k][ty * 4];
            float4 bb = *(const float4*)&Bs[k][tx * 4];
            acc[0][0] += a.x * bb.x; acc[0][1] += a.x * bb.y;
            acc[0][2] += a.x * bb.z; acc[0][3] += a.x * bb.w;
            acc[1][0] += a.y * bb.x; acc[1][1] += a.y * bb.y;
            acc[1][2] += a.y * bb.z; acc[1][3] += a.y * bb.w;
            acc[2][0] += a.z * bb.x; acc[2][1] += a.z * bb.y;
            acc[2][2] += a.z * bb.z; acc[2][3] += a.z * bb.w;
            acc[3][0] += a.w * bb.x; acc[3][1] += a.w * bb.y;
            acc[3][2] += a.w * bb.z; acc[3][3] += a.w * bb.w;
        }
        __syncthreads();
    }

#pragma unroll
    for (int i = 0; i < 4; i++)
#pragma unroll
        for (int j = 0; j < 4; j++) {
            long off = (long)(m0 + ty * 4 + i) * DD + n0 + tx * 4 + j;
            float v = alpha * acc[i][j];
            if (beta != 0.0f) v += beta * Cb[off];
            Cb[off] = v;
        }
}

extern "C" void kernel_launch(void* const* d_in, const int* in_sizes, int n_in,
                              void* d_out, int out_size, void* d_ws, size_t ws_size,
                              hipStream_t stream) {
    const float* crd      = (const float*)d_in[0];
    const float* rot      = (const float*)d_in[1];
    const float* rot_init = (const float*)d_in[2];
    const float* trans    = (const float*)d_in[3];

    float* out   = (float*)d_out;
    float* y     = out;                          // [64,384,384] hartley
    float* yreal = out + (size_t)NB * DD * DD;   // [64,384,384] real image

    float* U = (float*)d_ws;          // [384,384]
    float* S = U + DD * DD;           // [384,384]
    float* P = S + DD * DD;           // [64,384,384] intermediate (~37.7 MB)

    size_t imgN = (size_t)NB * DD * DD;

    // y_real accumulates via atomics -> must start at zero (ws/out are poisoned)
    hipMemsetAsync(yreal, 0, imgN * sizeof(float), stream);

    gen_w<<<(DD * DD + 255) / 256, 256, 0, stream>>>(U, S);

    pose_splat<<<dim3(NATOM / 256, NB), 256, 0, stream>>>(crd, rot, rot_init, trans, yreal);

    dim3 g(DD / 64, DD / 64, NB);
    long sImg = (long)DD * DD;
    // y = U * (Yreal * U) - 2 * S * (Yreal * S)
    mm64<<<g, 256, 0, stream>>>(yreal, sImg, U, 0, P, sImg, 1.0f, 0.0f);
    mm64<<<g, 256, 0, stream>>>(U, 0, P, sImg, y, sImg, 1.0f, 0.0f);
    mm64<<<g, 256, 0, stream>>>(yreal, sImg, S, 0, P, sImg, 1.0f, 0.0f);
    mm64<<<g, 256, 0, stream>>>(S, 0, P, sImg, y, sImg, -2.0f, 1.0f);
}

// Round 2
// 1683.882 us; speedup vs baseline: 2.3974x; 2.3974x over previous
//
#include <hip/hip_runtime.h>

#define DD 384
#define NB 64
#define NATOM 8192
#define KW 11
#define TS 96          // splat tile size (384/96 = 4x4 tiles per image)
#define LIST 1024      // atom list super-chunk

// ---------------------------------------------------------------------------
// DFT-derived matrices: theta(u,m) = 2*pi*(u-192)*(m-192)/384
//   U = cos+sin (cas), S = sin. y_out = U*Y*U - 2*S*Y*S == Re(f)-Im(f)
// of the double-fftshifted 2D FFT (shifts folded into the phase).
// ---------------------------------------------------------------------------
__global__ void gen_w(float* __restrict__ U, float* __restrict__ S) {
    int idx = blockIdx.x * 256 + threadIdx.x;
    if (idx >= DD * DD) return;
    int u = idx / DD, m = idx % DD;
    int t = (u - 192) * (m - 192);
    int r = t % DD;
    if (r < 0) r += DD;
    float th = (float)r * (6.28318530717958647692f / (float)DD);
    float s = sinf(th), c = cosf(th);
    U[idx] = c + s;
    S[idx] = s;
}

// ---------------------------------------------------------------------------
// Pose: XY[b,n] = (x,y) of crd @ rot_init + trans, then @ rot[b]^T.
// ---------------------------------------------------------------------------
__global__ void pose_xy(const float* __restrict__ crd,
                        const float* __restrict__ rot,
                        const float* __restrict__ rot_init,
                        const float* __restrict__ trans,
                        float2* __restrict__ XY) {
    int idx = blockIdx.x * 256 + threadIdx.x;
    int b = idx >> 13;           // /8192
    const float* p = crd + (long)idx * 3;
    float x0 = p[0], y0 = p[1], z0 = p[2];
    float q0 = x0 * rot_init[0] + y0 * rot_init[3] + z0 * rot_init[6] + trans[0];
    float q1 = x0 * rot_init[1] + y0 * rot_init[4] + z0 * rot_init[7] + trans[1];
    float q2 = x0 * rot_init[2] + y0 * rot_init[5] + z0 * rot_init[8] + trans[2];
    const float* R = rot + b * 9;
    float2 o;
    o.x = q0 * R[0] + q1 * R[1] + q2 * R[2];
    o.y = q0 * R[3] + q1 * R[4] + q2 * R[5];
    XY[idx] = o;
}

// ---------------------------------------------------------------------------
// Tiled splat: one block owns a 96x96 tile of one image, accumulates in LDS.
// Phase A: compact atoms touching the tile into an LDS list.
// Phase B: distribute (atom x footprint-row) tasks over all 256 threads,
//          LDS atomicAdd per pixel.
// Phase C: coalesced float4 writeout (tiles partition the image; no global
//          atomics, no prior memset needed).
// ---------------------------------------------------------------------------
__global__ __launch_bounds__(256) void splat_tiled(const float2* __restrict__ XY,
                                                   float* __restrict__ img) {
    int b = blockIdx.z;
    int ox = blockIdx.x * TS, oy = blockIdx.y * TS;
    int tid = threadIdx.x;

    __shared__ float tile[TS * TS];
    __shared__ float sx[LIST], sy[LIST];
    __shared__ int cnt;

    for (int i = tid; i < TS * TS; i += 256) tile[i] = 0.0f;

    const float2* xy = XY + (long)b * NATOM;
    const float inv2s2 = 1.0f / 4.5f;

    for (int base = 0; base < NATOM; base += LIST) {
        __syncthreads();               // previous phase B done / tile zero done
        if (tid == 0) cnt = 0;
        __syncthreads();

        // Phase A: test + compact
        for (int sub = 0; sub < LIST; sub += 256) {
            float2 v = xy[base + sub + tid];
            int icx = (int)rintf(v.x + 192.0f);
            int icy = (int)rintf(v.y + 192.0f);
            bool hit = (icx >= ox - 5) & (icx <= ox + TS + 4) &
                       (icy >= oy - 5) & (icy <= oy + TS + 4);
            if (hit) {
                int s = atomicAdd(&cnt, 1);
                sx[s] = v.x; sy[s] = v.y;
            }
        }
        __syncthreads();

        // Phase B: row tasks
        int T = cnt * KW;
        for (int t = tid; t < T; t += 256) {
            int a = t / KW;
            int ky = t - a * KW;
            float X = sx[a], Y = sy[a];
            int icx = (int)rintf(X + 192.0f);
            int icy = (int)rintf(Y + 192.0f);
            int iy = icy + ky - 5;
            if (iy < oy || iy >= oy + TS) continue;
            float dy = (float)(iy - 192) - Y;
            float gy = __expf(-dy * dy * inv2s2);
            float* row = tile + (iy - oy) * TS - ox;
#pragma unroll
            for (int kx = 0; kx < KW; kx++) {
                int ix = icx + kx - 5;
                if (ix < ox || ix >= ox + TS) continue;
                float dx = (float)(ix - 192) - X;
                atomicAdd(row + ix, gy * __expf(-dx * dx * inv2s2));
            }
        }
    }
    __syncthreads();

    // Phase C: writeout
    float* dst = img + (long)b * DD * DD;
    for (int i = tid; i < (TS * TS) / 4; i += 256) {
        int ty = i / (TS / 4), tx4 = (i % (TS / 4)) * 4;
        *(float4*)(dst + (long)(oy + ty) * DD + ox + tx4) =
            *(const float4*)(tile + ty * TS + tx4);
    }
}

// ---------------------------------------------------------------------------
// Batched fp32 matmul: C[bz] = alpha * A[bz] x B[bz] + beta * C[bz]
// ---------------------------------------------------------------------------
__global__ __launch_bounds__(256) void mm64(const float* __restrict__ A, long sA,
                                            const float* __restrict__ Bm, long sB,
                                            float* __restrict__ C, long sC,
                                            float alpha, float beta) {
    int bz = blockIdx.z;
    const float* Ab = A + (long)bz * sA;
    const float* Bb = Bm + (long)bz * sB;
    float* Cb = C + (long)bz * sC;

    __shared__ float As[16][64];
    __shared__ float Bs[16][64];

    int t = threadIdx.x;
    int m0 = blockIdx.y * 64, n0 = blockIdx.x * 64;
    int tx = t & 15, ty = t >> 4;

    float acc[4][4];
#pragma unroll
    for (int i = 0; i < 4; i++)
#pragma unroll
        for (int j = 0; j < 4; j++) acc[i][j] = 0.0f;

    for (int k0 = 0; k0 < DD; k0 += 16) {
#pragma unroll
        for (int i = 0; i < 4; i++) {
            int idx = t + i * 256;
            int m = idx >> 4, k = idx & 15;
            As[k][m] = Ab[(long)(m0 + m) * DD + k0 + k];
            int kk = idx >> 6, n = idx & 63;
            Bs[kk][n] = Bb[(long)(k0 + kk) * DD + n0 + n];
        }
        __syncthreads();
#pragma unroll
        for (int k = 0; k < 16; k++) {
            float4 a = *(const float4*)&As[k][ty * 4];
            float4 bb = *(const float4*)&Bs[k][tx * 4];
            acc[0][0] += a.x * bb.x; acc[0][1] += a.x * bb.y;
            acc[0][2] += a.x * bb.z; acc[0][3] += a.x * bb.w;
            acc[1][0] += a.y * bb.x; acc[1][1] += a.y * bb.y;
            acc[1][2] += a.y * bb.z; acc[1][3] += a.y * bb.w;
            acc[2][0] += a.z * bb.x; acc[2][1] += a.z * bb.y;
            acc[2][2] += a.z * bb.z; acc[2][3] += a.z * bb.w;
            acc[3][0] += a.w * bb.x; acc[3][1] += a.w * bb.y;
            acc[3][2] += a.w * bb.z; acc[3][3] += a.w * bb.w;
        }
        __syncthreads();
    }

#pragma unroll
    for (int i = 0; i < 4; i++)
#pragma unroll
        for (int j = 0; j < 4; j++) {
            long off = (long)(m0 + ty * 4 + i) * DD + n0 + tx * 4 + j;
            float v = alpha * acc[i][j];
            if (beta != 0.0f) v += beta * Cb[off];
            Cb[off] = v;
        }
}

extern "C" void kernel_launch(void* const* d_in, const int* in_sizes, int n_in,
                              void* d_out, int out_size, void* d_ws, size_t ws_size,
                              hipStream_t stream) {
    const float* crd      = (const float*)d_in[0];
    const float* rot      = (const float*)d_in[1];
    const float* rot_init = (const float*)d_in[2];
    const float* trans    = (const float*)d_in[3];

    float* out   = (float*)d_out;
    float* y     = out;                          // [64,384,384] hartley
    float* yreal = out + (size_t)NB * DD * DD;   // [64,384,384] real image

    float* U = (float*)d_ws;          // [384,384]
    float* S = U + DD * DD;           // [384,384]
    float* P = S + DD * DD;           // [64,384,384] matmul intermediate
    float2* XY = (float2*)P;          // [64,8192] posed coords (reuses P; splat
                                      // phase and matmul phase are disjoint)

    pose_xy<<<(NB * NATOM) / 256, 256, 0, stream>>>(crd, rot, rot_init, trans, XY);

    splat_tiled<<<dim3(DD / TS, DD / TS, NB), 256, 0, stream>>>(XY, yreal);

    gen_w<<<(DD * DD + 255) / 256, 256, 0, stream>>>(U, S);

    dim3 g(DD / 64, DD / 64, NB);
    long sImg = (long)DD * DD;
    // y = U*(Y*U) - 2*S*(Y*S)
    mm64<<<g, 256, 0, stream>>>(yreal, sImg, U, 0, P, sImg, 1.0f, 0.0f);
    mm64<<<g, 256, 0, stream>>>(U, 0, P, sImg, y, sImg, 1.0f, 0.0f);
    mm64<<<g, 256, 0, stream>>>(yreal, sImg, S, 0, P, sImg, 1.0f, 0.0f);
    mm64<<<g, 256, 0, stream>>>(S, 0, P, sImg, y, sImg, -2.0f, 1.0f);
}

// Round 5
// 1517.021 us; speedup vs baseline: 2.6611x; 1.1100x over previous
//
#include <hip/hip_runtime.h>

#define DD 384
#define NB 64
#define NATOM 8192
#define KW 11
#define TS 48          // splat tile size (384/48 = 8x8 tiles per image)
#define LIST 1024      // atom list super-chunk

typedef short short8 __attribute__((ext_vector_type(8)));
typedef float f32x4 __attribute__((ext_vector_type(4)));

// float -> bf16 (RNE) as ushort
__device__ inline unsigned bf1(float a) {
    unsigned u = __float_as_uint(a);
    return (u + 0x7FFFu + ((u >> 16) & 1u)) >> 16;
}
__device__ inline unsigned bfpack(float a, float b) {
    return bf1(a) | (bf1(b) << 16);
}

// ---------------------------------------------------------------------------
// DFT-derived weights (bf16), exploiting symmetry of U=cas, S=sin:
//   Bt1 = [U; S]   (768x384)   stage-1 B operand (shared)
//   Bt2 = [U|-2S]  (384x768)   stage-2 B operand (shared)
// y = U*Y*U - 2*S*Y*S == Re(f)-Im(f) of double-fftshifted FFT2.
// ---------------------------------------------------------------------------
__global__ void gen_w(unsigned short* __restrict__ Bt1,
                      unsigned short* __restrict__ Bt2) {
    int idx = blockIdx.x * 256 + threadIdx.x;
    if (idx >= DD * DD) return;
    int i = idx / DD, j = idx % DD;
    int t = (i - 192) * (j - 192);
    int r = t % DD;
    if (r < 0) r += DD;
    float th = (float)r * (6.28318530717958647692f / (float)DD);
    float s = sinf(th), c = cosf(th);
    Bt1[i * DD + j] = (unsigned short)bf1(c + s);
    Bt1[(DD + i) * DD + j] = (unsigned short)bf1(s);
    Bt2[i * 768 + j] = (unsigned short)bf1(c + s);
    Bt2[i * 768 + 384 + j] = (unsigned short)bf1(-2.0f * s);
}

// ---------------------------------------------------------------------------
// Pose: XY[b,n] = (x,y) of crd @ rot_init + trans, then @ rot[b]^T.
// ---------------------------------------------------------------------------
__global__ void pose_xy(const float* __restrict__ crd,
                        const float* __restrict__ rot,
                        const float* __restrict__ rot_init,
                        const float* __restrict__ trans,
                        float2* __restrict__ XY) {
    int idx = blockIdx.x * 256 + threadIdx.x;
    int b = idx >> 13;
    const float* p = crd + (long)idx * 3;
    float x0 = p[0], y0 = p[1], z0 = p[2];
    float q0 = x0 * rot_init[0] + y0 * rot_init[3] + z0 * rot_init[6] + trans[0];
    float q1 = x0 * rot_init[1] + y0 * rot_init[4] + z0 * rot_init[7] + trans[1];
    float q2 = x0 * rot_init[2] + y0 * rot_init[5] + z0 * rot_init[8] + trans[2];
    const float* R = rot + b * 9;
    float2 o;
    o.x = q0 * R[0] + q1 * R[1] + q2 * R[2];
    o.y = q0 * R[3] + q1 * R[4] + q2 * R[5];
    XY[idx] = o;
}

// ---------------------------------------------------------------------------
// Tiled splat, 48x48 LDS tile per block.
// ---------------------------------------------------------------------------
__global__ __launch_bounds__(256) void splat_tiled(const float2* __restrict__ XY,
                                                   float* __restrict__ img) {
    int b = blockIdx.z;
    int ox = blockIdx.x * TS, oy = blockIdx.y * TS;
    int tid = threadIdx.x;
    int lane = tid & 63;

    __shared__ float tile[TS * TS];
    __shared__ float sx[LIST], sy[LIST];
    __shared__ int cnt;

    for (int i = tid; i < TS * TS; i += 256) tile[i] = 0.0f;

    const float2* xy = XY + (long)b * NATOM;
    const float inv2s2 = 1.0f / 4.5f;

    for (int base = 0; base < NATOM; base += LIST) {
        __syncthreads();
        if (tid == 0) cnt = 0;
        __syncthreads();

        // Phase A: test + wave-aggregated compaction
        for (int sub = 0; sub < LIST; sub += 256) {
            float2 v = xy[base + sub + tid];
            int icx = (int)rintf(v.x + 192.0f);
            int icy = (int)rintf(v.y + 192.0f);
            bool hit = (icx >= ox - 5) && (icx <= ox + TS + 4) &&
                       (icy >= oy - 5) && (icy <= oy + TS + 4);
            unsigned long long mb = __ballot(hit);
            int pre = __popcll(mb & ((1ull << lane) - 1ull));
            int tot = __popcll(mb);
            int bs = 0;
            if (lane == 0 && tot) bs = atomicAdd(&cnt, tot);
            bs = __shfl(bs, 0);
            if (hit) { sx[bs + pre] = v.x; sy[bs + pre] = v.y; }
        }
        __syncthreads();

        // Phase B: one atom per thread, gx/gy computed once
        int n = cnt;
        for (int a = tid; a < n; a += 256) {
            float X = sx[a], Y = sy[a];
            int icx = (int)rintf(X + 192.0f);
            int icy = (int)rintf(Y + 192.0f);
            float gx[KW], gy[KW];
#pragma unroll
            for (int k = 0; k < KW; k++) {
                float dx = (float)(icx + k - 5 - 192) - X;
                gx[k] = __expf(-dx * dx * inv2s2);
                float dy = (float)(icy + k - 5 - 192) - Y;
                gy[k] = __expf(-dy * dy * inv2s2);
            }
#pragma unroll
            for (int ky = 0; ky < KW; ky++) {
                int ty = icy + ky - 5 - oy;
                if ((unsigned)ty >= TS) continue;
                float gyv = gy[ky];
                float* row = tile + ty * TS;
#pragma unroll
                for (int kx = 0; kx < KW; kx++) {
                    int tx = icx + kx - 5 - ox;
                    if ((unsigned)tx >= TS) continue;
                    atomicAdd(row + tx, gyv * gx[kx]);
                }
            }
        }
    }
    __syncthreads();

    // Phase C: coalesced writeout (tiles partition the image; no memset)
    float* dst = img + (long)b * DD * DD;
    for (int i = tid; i < (TS * TS) / 4; i += 256) {
        int r = i / (TS / 4), c4 = (i % (TS / 4)) * 4;
        *(float4*)(dst + (long)(oy + r) * DD + ox + c4) =
            *(const float4*)(tile + r * TS + c4);
    }
}

// ---------------------------------------------------------------------------
// bf16 MFMA GEMM (round-3-proven config): C[i][j] = sum_k A[i][k] * Bg[j][k]
//   A:  batched, row-major M x K (fp32 converted on stage if AF32, else bf16)
//   Bg: shared, row-major N x K bf16
//   C:  bf16 if CBF16 else fp32, straight epilogue
// 128x128 block tile, BK=64, 4 waves x (4x4) 16x16x32 fragments.
// LDS fragment-major: frag = 64 lanes x 16B -> conflict-free b128 r/w.
// ---------------------------------------------------------------------------
template <bool AF32, bool CBF16>
__global__ __launch_bounds__(256) void gemm_mfma(const void* __restrict__ Ag, long sA,
                                                 const unsigned short* __restrict__ Bg,
                                                 void* __restrict__ Cg, long sC,
                                                 int K, int ldc) {
    __shared__ uint4 lds4[2048];  // A: [0,1024), B: [1024,2048)

    int bz = blockIdx.z;
    int m0 = blockIdx.y * 128, n0 = blockIdx.x * 128;
    int tid = threadIdx.x;
    int lane = tid & 63, w = tid >> 6;
    int wm = w >> 1, wn = w & 1;

    f32x4 acc[4][4];
#pragma unroll
    for (int i = 0; i < 4; i++)
#pragma unroll
        for (int j = 0; j < 4; j++) acc[i][j] = (f32x4){0.f, 0.f, 0.f, 0.f};

    const float* Af = (const float*)Ag + (long)bz * sA;
    const unsigned short* Ah = (const unsigned short*)Ag + (long)bz * sA;

    for (int k0 = 0; k0 < K; k0 += 64) {
        __syncthreads();
#pragma unroll
        for (int cc = 0; cc < 4; cc++) {
            int c = tid + cc * 256;           // 1024 chunks of 8 elements
            int m = c >> 3, kc = (c & 7) << 3;
            int li = ((m >> 4) * 2 + (kc >> 5)) * 64 +
                     ((m & 15) | (((kc >> 3) & 3) << 4));
            uint4 wv;
            if (AF32) {
                const float* p = Af + (long)(m0 + m) * K + k0 + kc;
                float4 lo = *(const float4*)p;
                float4 hi = *(const float4*)(p + 4);
                wv.x = bfpack(lo.x, lo.y); wv.y = bfpack(lo.z, lo.w);
                wv.z = bfpack(hi.x, hi.y); wv.w = bfpack(hi.z, hi.w);
            } else {
                wv = *(const uint4*)(Ah + (long)(m0 + m) * K + k0 + kc);
            }
            lds4[li] = wv;
            lds4[1024 + li] = *(const uint4*)(Bg + (long)(n0 + m) * K + k0 + kc);
        }
        __syncthreads();
#pragma unroll
        for (int ki = 0; ki < 2; ki++) {
            short8 a[4], bfr[4];
#pragma unroll
            for (int i = 0; i < 4; i++)
                a[i] = *(const short8*)&lds4[((wm * 4 + i) * 2 + ki) * 64 + lane];
#pragma unroll
            for (int j = 0; j < 4; j++)
                bfr[j] = *(const short8*)&lds4[1024 + ((wn * 4 + j) * 2 + ki) * 64 + lane];
#pragma unroll
            for (int i = 0; i < 4; i++)
#pragma unroll
                for (int j = 0; j < 4; j++)
                    acc[i][j] = __builtin_amdgcn_mfma_f32_16x16x32_bf16(
                        a[i], bfr[j], acc[i][j], 0, 0, 0);
        }
    }

    int quad = lane >> 4, col0 = lane & 15;
#pragma unroll
    for (int i = 0; i < 4; i++)
#pragma unroll
        for (int j = 0; j < 4; j++)
#pragma unroll
            for (int r = 0; r < 4; r++) {
                int row = m0 + (wm * 4 + i) * 16 + quad * 4 + r;
                int cc2 = n0 + (wn * 4 + j) * 16 + col0;
                if (CBF16)
                    ((unsigned short*)Cg + (long)bz * sC)[(long)row * ldc + cc2] =
                        (unsigned short)bf1(acc[i][j][r]);
                else
                    ((float*)Cg + (long)bz * sC)[(long)row * ldc + cc2] = acc[i][j][r];
            }
}

// ---------------------------------------------------------------------------
// In-place fold-transpose of Z [64][384][768] bf16: per image, transpose the
// left 384x384 block (cols 0..383) and the right 384x384 block (cols
// 384..767) independently. Thread (b,r,c) with r<c swaps the (r,c)/(c,r)
// pair in both blocks; each pair touched by exactly one thread.
// After this: Z[v][k<384] = (YU)[k][v], Z[v][k>=384] = (YS)[k-384][v].
// ---------------------------------------------------------------------------
__global__ __launch_bounds__(256) void fold_transpose(unsigned short* __restrict__ Z) {
    long idx = (long)blockIdx.x * 256 + threadIdx.x;
    int b = (int)(idx / (DD * DD));
    int rc = (int)(idx % (DD * DD));
    int r = rc / DD, c = rc % DD;
    if (r >= c) return;
    unsigned short* Zb = Z + (long)b * DD * 768;
    unsigned short t0 = Zb[r * 768 + c];
    Zb[r * 768 + c] = Zb[c * 768 + r];
    Zb[c * 768 + r] = t0;
    unsigned short t1 = Zb[r * 768 + 384 + c];
    Zb[r * 768 + 384 + c] = Zb[c * 768 + 384 + r];
    Zb[c * 768 + 384 + r] = t1;
}

// ---------------------------------------------------------------------------
// In-place fp32 transpose of y [64][384][384] (stage 2 produces y^T).
// ---------------------------------------------------------------------------
__global__ __launch_bounds__(256) void transpose_inplace_f32(float* __restrict__ Yo) {
    long idx = (long)blockIdx.x * 256 + threadIdx.x;
    int b = (int)(idx / (DD * DD));
    int rc = (int)(idx % (DD * DD));
    int r = rc / DD, c = rc % DD;
    if (r >= c) return;
    float* Yb = Yo + (long)b * DD * DD;
    float t = Yb[r * DD + c];
    Yb[r * DD + c] = Yb[c * DD + r];
    Yb[c * DD + r] = t;
}

extern "C" void kernel_launch(void* const* d_in, const int* in_sizes, int n_in,
                              void* d_out, int out_size, void* d_ws, size_t ws_size,
                              hipStream_t stream) {
    const float* crd      = (const float*)d_in[0];
    const float* rot      = (const float*)d_in[1];
    const float* rot_init = (const float*)d_in[2];
    const float* trans    = (const float*)d_in[3];

    float* out   = (float*)d_out;
    float* y     = out;                          // [64,384,384] hartley (fp32)
    float* yreal = out + (size_t)NB * DD * DD;   // [64,384,384] real image

    char* ws = (char*)d_ws;
    unsigned short* Bt1 = (unsigned short*)ws;              // [U;S]   768x384
    unsigned short* Bt2 = (unsigned short*)(ws + 589824);   // [U|-2S] 384x768
    unsigned short* Z   = (unsigned short*)(ws + 1179648);  // 64x384x768 bf16
    float2* XY = (float2*)(ws + 1179648);  // aliases Z; dead before Z written

    pose_xy<<<(NB * NATOM) / 256, 256, 0, stream>>>(crd, rot, rot_init, trans, XY);

    splat_tiled<<<dim3(DD / TS, DD / TS, NB), 256, 0, stream>>>(XY, yreal);

    gen_w<<<(DD * DD + 255) / 256, 256, 0, stream>>>(Bt1, Bt2);

    // Stage 1 (round-3-proven config): Z = [Y*U | Y*S]  (A fp32 -> C bf16)
    // M=384, N=768, K=384.
    gemm_mfma<true, true><<<dim3(6, 3, NB), 256, 0, stream>>>(
        (const void*)yreal, (long)DD * DD, Bt1, (void*)Z, (long)DD * 768, DD, 768);

    // Fold-transpose Z in place -> Zt[v][k] = (YU)[k][v] | (YS)[k-384][v]
    fold_transpose<<<(NB * DD * DD) / 256, 256, 0, stream>>>(Z);

    // Stage 2 (round-3-proven config): C2 = y^T
    //   C2[i][j] = sum_k Zt[i][k]*Bt2[j][k] = (U*Y*U - 2*S*Y*S)[j][i]
    // M=384, N=384, K=768.
    gemm_mfma<false, false><<<dim3(3, 3, NB), 256, 0, stream>>>(
        (const void*)Z, (long)DD * 768, Bt2, (void*)y, (long)DD * DD, 768, DD);

    // y^T -> y in place
    transpose_inplace_f32<<<(NB * DD * DD) / 256, 256, 0, stream>>>(y);
}

// Round 6
// 1509.980 us; speedup vs baseline: 2.6735x; 1.0047x over previous
//
#include <hip/hip_runtime.h>

#define DD 384
#define NB 64
#define NATOM 8192
#define KW 11
#define TS 48          // splat tile size (384/48 = 8x8 tiles per image)
#define LIST 1024      // atom list super-chunk

typedef short short8 __attribute__((ext_vector_type(8)));
typedef float f32x4 __attribute__((ext_vector_type(4)));

// float -> bf16 (RNE) as ushort
__device__ inline unsigned bf1(float a) {
    unsigned u = __float_as_uint(a);
    return (u + 0x7FFFu + ((u >> 16) & 1u)) >> 16;
}
__device__ inline unsigned bfpack(float a, float b) {
    return bf1(a) | (bf1(b) << 16);
}

// ---------------------------------------------------------------------------
// DFT-derived weights (bf16), exploiting symmetry of U=cas, S=sin:
//   Bt1 = [U; S]   (768x384)   stage-1 B operand (shared)
//   Bt2 = [U|-2S]  (384x768)   stage-2 B operand (shared)
// y = U*Y*U - 2*S*Y*S == Re(f)-Im(f) of double-fftshifted FFT2.
// ---------------------------------------------------------------------------
__global__ void gen_w(unsigned short* __restrict__ Bt1,
                      unsigned short* __restrict__ Bt2) {
    int idx = blockIdx.x * 256 + threadIdx.x;
    if (idx >= DD * DD) return;
    int i = idx / DD, j = idx % DD;
    int t = (i - 192) * (j - 192);
    int r = t % DD;
    if (r < 0) r += DD;
    float th = (float)r * (6.28318530717958647692f / (float)DD);
    float s = sinf(th), c = cosf(th);
    Bt1[i * DD + j] = (unsigned short)bf1(c + s);
    Bt1[(DD + i) * DD + j] = (unsigned short)bf1(s);
    Bt2[i * 768 + j] = (unsigned short)bf1(c + s);
    Bt2[i * 768 + 384 + j] = (unsigned short)bf1(-2.0f * s);
}

// ---------------------------------------------------------------------------
// Pose: XY[b,n] = (x,y) of crd @ rot_init + trans, then @ rot[b]^T.
// ---------------------------------------------------------------------------
__global__ void pose_xy(const float* __restrict__ crd,
                        const float* __restrict__ rot,
                        const float* __restrict__ rot_init,
                        const float* __restrict__ trans,
                        float2* __restrict__ XY) {
    int idx = blockIdx.x * 256 + threadIdx.x;
    int b = idx >> 13;
    const float* p = crd + (long)idx * 3;
    float x0 = p[0], y0 = p[1], z0 = p[2];
    float q0 = x0 * rot_init[0] + y0 * rot_init[3] + z0 * rot_init[6] + trans[0];
    float q1 = x0 * rot_init[1] + y0 * rot_init[4] + z0 * rot_init[7] + trans[1];
    float q2 = x0 * rot_init[2] + y0 * rot_init[5] + z0 * rot_init[8] + trans[2];
    const float* R = rot + b * 9;
    float2 o;
    o.x = q0 * R[0] + q1 * R[1] + q2 * R[2];
    o.y = q0 * R[3] + q1 * R[4] + q2 * R[5];
    XY[idx] = o;
}

// ---------------------------------------------------------------------------
// Tiled splat, 48x48 LDS tile per block. Accumulation uses unsafeAtomicAdd
// (native ds_add_f32, fire-and-forget). Plain atomicAdd(float*) on LDS
// compiles to an IEEE-preserving CAS retry loop (~250 cyc dependent latency
// per add) — that was the entire round-2/round-5 splat bottleneck.
// ---------------------------------------------------------------------------
__global__ __launch_bounds__(256) void splat_tiled(const float2* __restrict__ XY,
                                                   float* __restrict__ img) {
    int b = blockIdx.z;
    int ox = blockIdx.x * TS, oy = blockIdx.y * TS;
    int tid = threadIdx.x;
    int lane = tid & 63;

    __shared__ float tile[TS * TS];
    __shared__ float sx[LIST], sy[LIST];
    __shared__ int cnt;

    for (int i = tid; i < TS * TS; i += 256) tile[i] = 0.0f;

    const float2* xy = XY + (long)b * NATOM;
    const float inv2s2 = 1.0f / 4.5f;

    for (int base = 0; base < NATOM; base += LIST) {
        __syncthreads();
        if (tid == 0) cnt = 0;
        __syncthreads();

        // Phase A: test + wave-aggregated compaction
        for (int sub = 0; sub < LIST; sub += 256) {
            float2 v = xy[base + sub + tid];
            int icx = (int)rintf(v.x + 192.0f);
            int icy = (int)rintf(v.y + 192.0f);
            bool hit = (icx >= ox - 5) && (icx <= ox + TS + 4) &&
                       (icy >= oy - 5) && (icy <= oy + TS + 4);
            unsigned long long mb = __ballot(hit);
            int pre = __popcll(mb & ((1ull << lane) - 1ull));
            int tot = __popcll(mb);
            int bs = 0;
            if (lane == 0 && tot) bs = atomicAdd(&cnt, tot);
            bs = __shfl(bs, 0);
            if (hit) { sx[bs + pre] = v.x; sy[bs + pre] = v.y; }
        }
        __syncthreads();

        // Phase B: one atom per thread, gx/gy computed once
        int n = cnt;
        for (int a = tid; a < n; a += 256) {
            float X = sx[a], Y = sy[a];
            int icx = (int)rintf(X + 192.0f);
            int icy = (int)rintf(Y + 192.0f);
            float gx[KW], gy[KW];
#pragma unroll
            for (int k = 0; k < KW; k++) {
                float dx = (float)(icx + k - 5 - 192) - X;
                gx[k] = __expf(-dx * dx * inv2s2);
                float dy = (float)(icy + k - 5 - 192) - Y;
                gy[k] = __expf(-dy * dy * inv2s2);
            }
#pragma unroll
            for (int ky = 0; ky < KW; ky++) {
                int ty = icy + ky - 5 - oy;
                if ((unsigned)ty >= TS) continue;
                float gyv = gy[ky];
                float* row = tile + ty * TS;
#pragma unroll
                for (int kx = 0; kx < KW; kx++) {
                    int tx = icx + kx - 5 - ox;
                    if ((unsigned)tx >= TS) continue;
                    unsafeAtomicAdd(row + tx, gyv * gx[kx]);
                }
            }
        }
    }
    __syncthreads();

    // Phase C: coalesced writeout (tiles partition the image; no memset)
    float* dst = img + (long)b * DD * DD;
    for (int i = tid; i < (TS * TS) / 4; i += 256) {
        int r = i / (TS / 4), c4 = (i % (TS / 4)) * 4;
        *(float4*)(dst + (long)(oy + r) * DD + ox + c4) =
            *(const float4*)(tile + r * TS + c4);
    }
}

// ---------------------------------------------------------------------------
// bf16 MFMA GEMM (round-3-proven config): C[i][j] = sum_k A[i][k] * Bg[j][k]
//   A:  batched, row-major M x K (fp32 converted on stage if AF32, else bf16)
//   Bg: shared, row-major N x K bf16
//   C:  bf16 if CBF16 else fp32, straight epilogue
// 128x128 block tile, BK=64, 4 waves x (4x4) 16x16x32 fragments.
// LDS fragment-major: frag = 64 lanes x 16B -> conflict-free b128 r/w.
// ---------------------------------------------------------------------------
template <bool AF32, bool CBF16>
__global__ __launch_bounds__(256) void gemm_mfma(const void* __restrict__ Ag, long sA,
                                                 const unsigned short* __restrict__ Bg,
                                                 void* __restrict__ Cg, long sC,
                                                 int K, int ldc) {
    __shared__ uint4 lds4[2048];  // A: [0,1024), B: [1024,2048)

    int bz = blockIdx.z;
    int m0 = blockIdx.y * 128, n0 = blockIdx.x * 128;
    int tid = threadIdx.x;
    int lane = tid & 63, w = tid >> 6;
    int wm = w >> 1, wn = w & 1;

    f32x4 acc[4][4];
#pragma unroll
    for (int i = 0; i < 4; i++)
#pragma unroll
        for (int j = 0; j < 4; j++) acc[i][j] = (f32x4){0.f, 0.f, 0.f, 0.f};

    const float* Af = (const float*)Ag + (long)bz * sA;
    const unsigned short* Ah = (const unsigned short*)Ag + (long)bz * sA;

    for (int k0 = 0; k0 < K; k0 += 64) {
        __syncthreads();
#pragma unroll
        for (int cc = 0; cc < 4; cc++) {
            int c = tid + cc * 256;           // 1024 chunks of 8 elements
            int m = c >> 3, kc = (c & 7) << 3;
            int li = ((m >> 4) * 2 + (kc >> 5)) * 64 +
                     ((m & 15) | (((kc >> 3) & 3) << 4));
            uint4 wv;
            if (AF32) {
                const float* p = Af + (long)(m0 + m) * K + k0 + kc;
                float4 lo = *(const float4*)p;
                float4 hi = *(const float4*)(p + 4);
                wv.x = bfpack(lo.x, lo.y); wv.y = bfpack(lo.z, lo.w);
                wv.z = bfpack(hi.x, hi.y); wv.w = bfpack(hi.z, hi.w);
            } else {
                wv = *(const uint4*)(Ah + (long)(m0 + m) * K + k0 + kc);
            }
            lds4[li] = wv;
            lds4[1024 + li] = *(const uint4*)(Bg + (long)(n0 + m) * K + k0 + kc);
        }
        __syncthreads();
#pragma unroll
        for (int ki = 0; ki < 2; ki++) {
            short8 a[4], bfr[4];
#pragma unroll
            for (int i = 0; i < 4; i++)
                a[i] = *(const short8*)&lds4[((wm * 4 + i) * 2 + ki) * 64 + lane];
#pragma unroll
            for (int j = 0; j < 4; j++)
                bfr[j] = *(const short8*)&lds4[1024 + ((wn * 4 + j) * 2 + ki) * 64 + lane];
#pragma unroll
            for (int i = 0; i < 4; i++)
#pragma unroll
                for (int j = 0; j < 4; j++)
                    acc[i][j] = __builtin_amdgcn_mfma_f32_16x16x32_bf16(
                        a[i], bfr[j], acc[i][j], 0, 0, 0);
        }
    }

    int quad = lane >> 4, col0 = lane & 15;
#pragma unroll
    for (int i = 0; i < 4; i++)
#pragma unroll
        for (int j = 0; j < 4; j++)
#pragma unroll
            for (int r = 0; r < 4; r++) {
                int row = m0 + (wm * 4 + i) * 16 + quad * 4 + r;
                int cc2 = n0 + (wn * 4 + j) * 16 + col0;
                if (CBF16)
                    ((unsigned short*)Cg + (long)bz * sC)[(long)row * ldc + cc2] =
                        (unsigned short)bf1(acc[i][j][r]);
                else
                    ((float*)Cg + (long)bz * sC)[(long)row * ldc + cc2] = acc[i][j][r];
            }
}

// ---------------------------------------------------------------------------
// In-place fold-transpose of Z [64][384][768] bf16: per image, transpose the
// left and right 384x384 blocks independently (one thread per r<c pair).
// After this: Z[v][k<384] = (YU)[k][v], Z[v][k>=384] = (YS)[k-384][v].
// ---------------------------------------------------------------------------
__global__ __launch_bounds__(256) void fold_transpose(unsigned short* __restrict__ Z) {
    long idx = (long)blockIdx.x * 256 + threadIdx.x;
    int b = (int)(idx / (DD * DD));
    int rc = (int)(idx % (DD * DD));
    int r = rc / DD, c = rc % DD;
    if (r >= c) return;
    unsigned short* Zb = Z + (long)b * DD * 768;
    unsigned short t0 = Zb[r * 768 + c];
    Zb[r * 768 + c] = Zb[c * 768 + r];
    Zb[c * 768 + r] = t0;
    unsigned short t1 = Zb[r * 768 + 384 + c];
    Zb[r * 768 + 384 + c] = Zb[c * 768 + 384 + r];
    Zb[c * 768 + 384 + r] = t1;
}

// ---------------------------------------------------------------------------
// In-place fp32 transpose of y [64][384][384] (stage 2 produces y^T).
// ---------------------------------------------------------------------------
__global__ __launch_bounds__(256) void transpose_inplace_f32(float* __restrict__ Yo) {
    long idx = (long)blockIdx.x * 256 + threadIdx.x;
    int b = (int)(idx / (DD * DD));
    int rc = (int)(idx % (DD * DD));
    int r = rc / DD, c = rc % DD;
    if (r >= c) return;
    float* Yb = Yo + (long)b * DD * DD;
    float t = Yb[r * DD + c];
    Yb[r * DD + c] = Yb[c * DD + r];
    Yb[c * DD + r] = t;
}

extern "C" void kernel_launch(void* const* d_in, const int* in_sizes, int n_in,
                              void* d_out, int out_size, void* d_ws, size_t ws_size,
                              hipStream_t stream) {
    const float* crd      = (const float*)d_in[0];
    const float* rot      = (const float*)d_in[1];
    const float* rot_init = (const float*)d_in[2];
    const float* trans    = (const float*)d_in[3];

    float* out   = (float*)d_out;
    float* y     = out;                          // [64,384,384] hartley (fp32)
    float* yreal = out + (size_t)NB * DD * DD;   // [64,384,384] real image

    char* ws = (char*)d_ws;
    unsigned short* Bt1 = (unsigned short*)ws;              // [U;S]   768x384
    unsigned short* Bt2 = (unsigned short*)(ws + 589824);   // [U|-2S] 384x768
    unsigned short* Z   = (unsigned short*)(ws + 1179648);  // 64x384x768 bf16
    float2* XY = (float2*)(ws + 1179648);  // aliases Z; dead before Z written

    pose_xy<<<(NB * NATOM) / 256, 256, 0, stream>>>(crd, rot, rot_init, trans, XY);

    splat_tiled<<<dim3(DD / TS, DD / TS, NB), 256, 0, stream>>>(XY, yreal);

    gen_w<<<(DD * DD + 255) / 256, 256, 0, stream>>>(Bt1, Bt2);

    // Stage 1: Z = [Y*U | Y*S]  (A fp32 -> C bf16), M=384, N=768, K=384.
    gemm_mfma<true, true><<<dim3(6, 3, NB), 256, 0, stream>>>(
        (const void*)yreal, (long)DD * DD, Bt1, (void*)Z, (long)DD * 768, DD, 768);

    // Fold-transpose Z in place -> Zt[v][k] = (YU)[k][v] | (YS)[k-384][v]
    fold_transpose<<<(NB * DD * DD) / 256, 256, 0, stream>>>(Z);

    // Stage 2: C2 = y^T  (C2[i][j] = sum_k Zt[i][k]*Bt2[j][k]), M=N=384, K=768.
    gemm_mfma<false, false><<<dim3(3, 3, NB), 256, 0, stream>>>(
        (const void*)Z, (long)DD * 768, Bt2, (void*)y, (long)DD * DD, 768, DD);

    // y^T -> y in place
    transpose_inplace_f32<<<(NB * DD * DD) / 256, 256, 0, stream>>>(y);
}

// Round 7
// 637.464 us; speedup vs baseline: 6.3328x; 2.3687x over previous
//
#include <hip/hip_runtime.h>

#define DD 384
#define NB 64
#define NATOM 8192
#define RB 394              // row buckets: icy+5, icy in [-5,388]
#define CB 26               // col buckets: (icx+16)>>4, icx in [-5,388]
#define NBKT (RB * CB)      // 10244
#define OFFSTRIDE (NBKT + 4)

typedef short short8 __attribute__((ext_vector_type(8)));
typedef float f32x4 __attribute__((ext_vector_type(4)));

// float -> bf16 (RNE) as ushort
__device__ inline unsigned bf1(float a) {
    unsigned u = __float_as_uint(a);
    return (u + 0x7FFFu + ((u >> 16) & 1u)) >> 16;
}
__device__ inline unsigned bfpack(float a, float b) {
    return bf1(a) | (bf1(b) << 16);
}

// Pose one atom -> (X, Y) in physical coords (identical code in count/scatter
// => bit-identical results).
__device__ inline float2 pose_one(const float* __restrict__ crd,
                                  const float* __restrict__ rot,
                                  const float* __restrict__ rot_init,
                                  const float* __restrict__ trans, int idx) {
    int b = idx >> 13;
    const float* p = crd + (long)idx * 3;
    float x0 = p[0], y0 = p[1], z0 = p[2];
    float q0 = x0 * rot_init[0] + y0 * rot_init[3] + z0 * rot_init[6] + trans[0];
    float q1 = x0 * rot_init[1] + y0 * rot_init[4] + z0 * rot_init[7] + trans[1];
    float q2 = x0 * rot_init[2] + y0 * rot_init[5] + z0 * rot_init[8] + trans[2];
    const float* R = rot + b * 9;
    float2 o;
    o.x = q0 * R[0] + q1 * R[1] + q2 * R[2];
    o.y = q0 * R[3] + q1 * R[4] + q2 * R[5];
    return o;
}

// ---------------------------------------------------------------------------
// Bucketing: count -> per-image flat exclusive scan -> scatter.
// ---------------------------------------------------------------------------
__global__ void count_atoms(const float* __restrict__ crd,
                            const float* __restrict__ rot,
                            const float* __restrict__ rot_init,
                            const float* __restrict__ trans,
                            int* __restrict__ counts) {
    int idx = blockIdx.x * 256 + threadIdx.x;
    float2 v = pose_one(crd, rot, rot_init, trans, idx);
    int icx = (int)rintf(v.x + 192.0f);
    int icy = (int)rintf(v.y + 192.0f);
    if (icx < -5 || icx > 388 || icy < -5 || icy > 388) return;
    int bi = (icy + 5) * CB + ((icx + 16) >> 4);
    atomicAdd(&counts[(idx >> 13) * NBKT + bi], 1);
}

__global__ __launch_bounds__(256) void bucket_scan(int* __restrict__ counts,
                                                   int* __restrict__ offs) {
    int b = blockIdx.x, t = threadIdx.x;
    const int PER = (NBKT + 255) / 256;  // 41
    int* cnt = counts + b * NBKT;
    int* off = offs + b * OFFSTRIDE;
    int base = t * PER;
    int s = 0;
    for (int i = 0; i < PER; i++) {
        int k = base + i;
        if (k < NBKT) s += cnt[k];
    }
    __shared__ int part[256];
    part[t] = s;
    __syncthreads();
    for (int d = 1; d < 256; d <<= 1) {
        int v = (t >= d) ? part[t - d] : 0;
        __syncthreads();
        part[t] += v;
        __syncthreads();
    }
    int run = (t == 0) ? 0 : part[t - 1];
    for (int i = 0; i < PER; i++) {
        int k = base + i;
        if (k < NBKT) {
            off[k] = run;
            run += cnt[k];
            cnt[k] = 0;  // reuse as scatter cursor
        }
    }
    if (base <= NBKT - 1 && NBKT - 1 < base + PER) off[NBKT] = run;  // total
}

__global__ void scatter_atoms(const float* __restrict__ crd,
                              const float* __restrict__ rot,
                              const float* __restrict__ rot_init,
                              const float* __restrict__ trans,
                              int* __restrict__ cursors,
                              const int* __restrict__ offs,
                              float2* __restrict__ sorted) {
    int idx = blockIdx.x * 256 + threadIdx.x;
    float2 v = pose_one(crd, rot, rot_init, trans, idx);
    int icx = (int)rintf(v.x + 192.0f);
    int icy = (int)rintf(v.y + 192.0f);
    if (icx < -5 || icx > 388 || icy < -5 || icy > 388) return;
    int b = idx >> 13;
    int bi = (icy + 5) * CB + ((icx + 16) >> 4);
    int pos = offs[b * OFFSTRIDE + bi] + atomicAdd(&cursors[b * NBKT + bi], 1);
    sorted[(long)b * NATOM + pos] = v;
}

// ---------------------------------------------------------------------------
// Atomic-free gather splat. Wave owns 4 rows x 384 px; lane owns 6 px in
// registers. Lane walks only the <=2 col-buckets overlapping its +-5 window
// across the 14 row-buckets feeding its 4 rows. Every (atom,row,px) pair is
// accumulated by exactly one lane -> pure FMA, no atomics, no LDS.
// ---------------------------------------------------------------------------
__global__ __launch_bounds__(256) void splat_rows(const float2* __restrict__ sorted,
                                                  const int* __restrict__ offs,
                                                  float* __restrict__ img) {
    int b = blockIdx.y;
    int r0 = blockIdx.x * 16 + ((threadIdx.x >> 6) << 2);  // 4 rows per wave
    int lane = threadIdx.x & 63;
    int p0 = lane * 6;                                     // 6 owned px
    const float c = 1.0f / 4.5f;
    const int* off = offs + b * OFFSTRIDE;
    const float2* srt = sorted + (long)b * NATOM;

    float acc[4][6];
#pragma unroll
    for (int r = 0; r < 4; r++)
#pragma unroll
        for (int k = 0; k < 6; k++) acc[r][k] = 0.0f;

    int cb_lo = (p0 + 11) >> 4;  // icx >= p0-5  -> cb >= this
    int cb_hi = (p0 + 26) >> 4;  // icx <= p0+10 -> cb <= this

    for (int rb = r0; rb < r0 + 14; rb++) {   // icy in [r0-5, r0+8]
        int icy = rb - 5;
        for (int cb = cb_lo; cb <= cb_hi; cb++) {
            int i0 = off[rb * CB + cb];
            int i1 = off[rb * CB + cb + 1];   // flat scan: next bucket's start
            for (int i = i0; i < i1; i++) {
                float2 v = srt[i];
                float X = v.x, Yc = v.y;
                int icx = (int)rintf(X + 192.0f);
                float gx[6];
#pragma unroll
                for (int k = 0; k < 6; k++) {
                    int p = p0 + k;
                    float dx = (float)(p - 192) - X;
                    bool m = ((unsigned)(p - icx + 5)) < 11u;  // |p-icx|<=5
                    gx[k] = m ? __expf(-dx * dx * c) : 0.0f;
                }
#pragma unroll
                for (int r = 0; r < 4; r++) {
                    int row = r0 + r;
                    float dy = (float)(row - 192) - Yc;
                    bool m = ((unsigned)(row - icy + 5)) < 11u;  // |row-icy|<=5
                    float gy = m ? __expf(-dy * dy * c) : 0.0f;
#pragma unroll
                    for (int k = 0; k < 6; k++) acc[r][k] += gy * gx[k];
                }
            }
        }
    }

#pragma unroll
    for (int r = 0; r < 4; r++) {
        float* dst = img + ((long)b * DD + r0 + r) * DD + p0;
#pragma unroll
        for (int k = 0; k < 6; k++) dst[k] = acc[r][k];
    }
}

// ---------------------------------------------------------------------------
// DFT-derived weights (bf16): Bt1 = [U; S] (768x384), Bt2 = [U|-2S] (384x768).
// y = U*Y*U - 2*S*Y*S == Re(f)-Im(f) of double-fftshifted FFT2.
// ---------------------------------------------------------------------------
__global__ void gen_w(unsigned short* __restrict__ Bt1,
                      unsigned short* __restrict__ Bt2) {
    int idx = blockIdx.x * 256 + threadIdx.x;
    if (idx >= DD * DD) return;
    int i = idx / DD, j = idx % DD;
    int t = (i - 192) * (j - 192);
    int r = t % DD;
    if (r < 0) r += DD;
    float th = (float)r * (6.28318530717958647692f / (float)DD);
    float s = sinf(th), c = cosf(th);
    Bt1[i * DD + j] = (unsigned short)bf1(c + s);
    Bt1[(DD + i) * DD + j] = (unsigned short)bf1(s);
    Bt2[i * 768 + j] = (unsigned short)bf1(c + s);
    Bt2[i * 768 + 384 + j] = (unsigned short)bf1(-2.0f * s);
}

// ---------------------------------------------------------------------------
// bf16 MFMA GEMM (proven config): C[i][j] = sum_k A[i][k] * Bg[j][k]
// ---------------------------------------------------------------------------
template <bool AF32, bool CBF16>
__global__ __launch_bounds__(256) void gemm_mfma(const void* __restrict__ Ag, long sA,
                                                 const unsigned short* __restrict__ Bg,
                                                 void* __restrict__ Cg, long sC,
                                                 int K, int ldc) {
    __shared__ uint4 lds4[2048];  // A: [0,1024), B: [1024,2048)

    int bz = blockIdx.z;
    int m0 = blockIdx.y * 128, n0 = blockIdx.x * 128;
    int tid = threadIdx.x;
    int lane = tid & 63, w = tid >> 6;
    int wm = w >> 1, wn = w & 1;

    f32x4 acc[4][4];
#pragma unroll
    for (int i = 0; i < 4; i++)
#pragma unroll
        for (int j = 0; j < 4; j++) acc[i][j] = (f32x4){0.f, 0.f, 0.f, 0.f};

    const float* Af = (const float*)Ag + (long)bz * sA;
    const unsigned short* Ah = (const unsigned short*)Ag + (long)bz * sA;

    for (int k0 = 0; k0 < K; k0 += 64) {
        __syncthreads();
#pragma unroll
        for (int cc = 0; cc < 4; cc++) {
            int c = tid + cc * 256;
            int m = c >> 3, kc = (c & 7) << 3;
            int li = ((m >> 4) * 2 + (kc >> 5)) * 64 +
                     ((m & 15) | (((kc >> 3) & 3) << 4));
            uint4 wv;
            if (AF32) {
                const float* p = Af + (long)(m0 + m) * K + k0 + kc;
                float4 lo = *(const float4*)p;
                float4 hi = *(const float4*)(p + 4);
                wv.x = bfpack(lo.x, lo.y); wv.y = bfpack(lo.z, lo.w);
                wv.z = bfpack(hi.x, hi.y); wv.w = bfpack(hi.z, hi.w);
            } else {
                wv = *(const uint4*)(Ah + (long)(m0 + m) * K + k0 + kc);
            }
            lds4[li] = wv;
            lds4[1024 + li] = *(const uint4*)(Bg + (long)(n0 + m) * K + k0 + kc);
        }
        __syncthreads();
#pragma unroll
        for (int ki = 0; ki < 2; ki++) {
            short8 a[4], bfr[4];
#pragma unroll
            for (int i = 0; i < 4; i++)
                a[i] = *(const short8*)&lds4[((wm * 4 + i) * 2 + ki) * 64 + lane];
#pragma unroll
            for (int j = 0; j < 4; j++)
                bfr[j] = *(const short8*)&lds4[1024 + ((wn * 4 + j) * 2 + ki) * 64 + lane];
#pragma unroll
            for (int i = 0; i < 4; i++)
#pragma unroll
                for (int j = 0; j < 4; j++)
                    acc[i][j] = __builtin_amdgcn_mfma_f32_16x16x32_bf16(
                        a[i], bfr[j], acc[i][j], 0, 0, 0);
        }
    }

    int quad = lane >> 4, col0 = lane & 15;
#pragma unroll
    for (int i = 0; i < 4; i++)
#pragma unroll
        for (int j = 0; j < 4; j++)
#pragma unroll
            for (int r = 0; r < 4; r++) {
                int row = m0 + (wm * 4 + i) * 16 + quad * 4 + r;
                int cc2 = n0 + (wn * 4 + j) * 16 + col0;
                if (CBF16)
                    ((unsigned short*)Cg + (long)bz * sC)[(long)row * ldc + cc2] =
                        (unsigned short)bf1(acc[i][j][r]);
                else
                    ((float*)Cg + (long)bz * sC)[(long)row * ldc + cc2] = acc[i][j][r];
            }
}

// ---------------------------------------------------------------------------
// In-place fold-transpose of Z [64][384][768] bf16 (left/right 384x384 blocks
// transposed independently; one thread per r<c pair).
// ---------------------------------------------------------------------------
__global__ __launch_bounds__(256) void fold_transpose(unsigned short* __restrict__ Z) {
    long idx = (long)blockIdx.x * 256 + threadIdx.x;
    int b = (int)(idx / (DD * DD));
    int rc = (int)(idx % (DD * DD));
    int r = rc / DD, c = rc % DD;
    if (r >= c) return;
    unsigned short* Zb = Z + (long)b * DD * 768;
    unsigned short t0 = Zb[r * 768 + c];
    Zb[r * 768 + c] = Zb[c * 768 + r];
    Zb[c * 768 + r] = t0;
    unsigned short t1 = Zb[r * 768 + 384 + c];
    Zb[r * 768 + 384 + c] = Zb[c * 768 + 384 + r];
    Zb[c * 768 + 384 + r] = t1;
}

// ---------------------------------------------------------------------------
// In-place fp32 transpose of y [64][384][384] (stage 2 produces y^T).
// ---------------------------------------------------------------------------
__global__ __launch_bounds__(256) void transpose_inplace_f32(float* __restrict__ Yo) {
    long idx = (long)blockIdx.x * 256 + threadIdx.x;
    int b = (int)(idx / (DD * DD));
    int rc = (int)(idx % (DD * DD));
    int r = rc / DD, c = rc % DD;
    if (r >= c) return;
    float* Yb = Yo + (long)b * DD * DD;
    float t = Yb[r * DD + c];
    Yb[r * DD + c] = Yb[c * DD + r];
    Yb[c * DD + r] = t;
}

extern "C" void kernel_launch(void* const* d_in, const int* in_sizes, int n_in,
                              void* d_out, int out_size, void* d_ws, size_t ws_size,
                              hipStream_t stream) {
    const float* crd      = (const float*)d_in[0];
    const float* rot      = (const float*)d_in[1];
    const float* rot_init = (const float*)d_in[2];
    const float* trans    = (const float*)d_in[3];

    float* out   = (float*)d_out;
    float* y     = out;                          // [64,384,384] hartley (fp32)
    float* yreal = out + (size_t)NB * DD * DD;   // [64,384,384] real image

    char* ws = (char*)d_ws;
    unsigned short* Bt1 = (unsigned short*)ws;              // [U;S]   768x384
    unsigned short* Bt2 = (unsigned short*)(ws + 589824);   // [U|-2S] 384x768
    char* Zb = ws + 1179648;                                // Z region (37.7MB)
    unsigned short* Z = (unsigned short*)Zb;                // 64x384x768 bf16
    // Bucketing scratch aliases Z (all dead before stage-1 GEMM writes Z):
    int*    counts = (int*)Zb;                              // 2,622,464 B
    int*    offs   = (int*)(Zb + 2622464);                  // 2,623,488 B
    float2* sorted = (float2*)(Zb + 5245952);               // 4,194,304 B

    hipMemsetAsync(counts, 0, (size_t)NB * NBKT * 4, stream);

    count_atoms<<<(NB * NATOM) / 256, 256, 0, stream>>>(crd, rot, rot_init, trans, counts);
    bucket_scan<<<NB, 256, 0, stream>>>(counts, offs);
    scatter_atoms<<<(NB * NATOM) / 256, 256, 0, stream>>>(crd, rot, rot_init, trans,
                                                          counts, offs, sorted);
    splat_rows<<<dim3(24, NB), 256, 0, stream>>>(sorted, offs, yreal);

    gen_w<<<(DD * DD + 255) / 256, 256, 0, stream>>>(Bt1, Bt2);

    // Stage 1: Z = [Y*U | Y*S]  (A fp32 -> C bf16), M=384, N=768, K=384.
    gemm_mfma<true, true><<<dim3(6, 3, NB), 256, 0, stream>>>(
        (const void*)yreal, (long)DD * DD, Bt1, (void*)Z, (long)DD * 768, DD, 768);

    // Fold-transpose Z in place -> Zt[v][k] = (YU)[k][v] | (YS)[k-384][v]
    fold_transpose<<<(NB * DD * DD) / 256, 256, 0, stream>>>(Z);

    // Stage 2: C2 = y^T  (C2[i][j] = sum_k Zt[i][k]*Bt2[j][k]), M=N=384, K=768.
    gemm_mfma<false, false><<<dim3(3, 3, NB), 256, 0, stream>>>(
        (const void*)Z, (long)DD * 768, Bt2, (void*)y, (long)DD * DD, 768, DD);

    // y^T -> y in place
    transpose_inplace_f32<<<(NB * DD * DD) / 256, 256, 0, stream>>>(y);
}